// Round 1
// baseline (209.830 us; speedup 1.0000x reference)
//
#include <hip/hip_runtime.h>
#include <hip/hip_bf16.h>
#include <cstdint>

// Problem constants (match reference)
constexpr int NB = 4;        // batch
constexpr int NV = 8192;     // vertices
constexpr int NF = 16384;    // faces
constexpr int NP = 8192;     // query points per batch
constexpr float F_EPS = 1e-3f;
constexpr float F_WEIGHT = 1000.0f;

// nn_kernel tiling
constexpr int SLICES   = 8;               // F split across blocks
constexpr int SLICE_F  = NF / SLICES;     // 2048 centers per slice (32KB LDS)
constexpr int CHUNKS   = 8;               // N split across blocks
constexpr int CHUNK_P  = NP / CHUNKS;     // 1024 points per chunk
constexpr int TPB      = 256;
constexpr int PPT      = CHUNK_P / TPB;   // 4 points per thread

// ---------------------------------------------------------------------------
// Kernel A: per-face centers (xyz + ||c||^2) and unit normals, packed float4
// ---------------------------------------------------------------------------
__global__ void centers_kernel(const float* __restrict__ pos,    // [B,V,3]
                               const int*   __restrict__ faces,  // [B,F,3]
                               float4* __restrict__ centers4,    // [B*F]
                               float4* __restrict__ normals4) {  // [B*F]
    int i = blockIdx.x * blockDim.x + threadIdx.x;
    if (i >= NB * NF) return;
    int b = i / NF;
    const float* p = pos + (size_t)b * NV * 3;
    int i0 = faces[3 * i + 0];
    int i1 = faces[3 * i + 1];
    int i2 = faces[3 * i + 2];
    float ax = p[3 * i0], ay = p[3 * i0 + 1], az = p[3 * i0 + 2];
    float bx = p[3 * i1], by = p[3 * i1 + 1], bz = p[3 * i1 + 2];
    float cx = p[3 * i2], cy = p[3 * i2 + 1], cz = p[3 * i2 + 2];

    const float third = 1.0f / 3.0f;
    float mx = (ax + bx + cx) * third;
    float my = (ay + by + cy) * third;
    float mz = (az + bz + cz) * third;
    float c2 = mx * mx + my * my + mz * mz;

    float e1x = bx - ax, e1y = by - ay, e1z = bz - az;
    float e2x = cx - ax, e2y = cy - ay, e2z = cz - az;
    float nx = e1y * e2z - e1z * e2y;
    float ny = e1z * e2x - e1x * e2z;
    float nz = e1x * e2y - e1y * e2x;
    float len = sqrtf(nx * nx + ny * ny + nz * nz);
    float inv = 1.0f / fmaxf(len, 1e-12f);

    centers4[i] = make_float4(mx, my, mz, c2);
    normals4[i] = make_float4(nx * inv, ny * inv, nz * inv, 0.0f);
}

// ---------------------------------------------------------------------------
// Kernel B: 1-NN scan. Block = (chunk, slice, batch). LDS-staged centers,
// register-blocked points; cross-slice merge via packed atomicMin key:
//   key = (bits(max(d + ||p||^2, 0)) & 0xFFFFC000) | global_face_idx
// ||p-c||^2 >= 0 so float bits order as uint; low 14 bits hold idx (F=16384).
// ---------------------------------------------------------------------------
__global__ __launch_bounds__(TPB) void nn_kernel(
        const float* __restrict__ pred,        // [B,N,3]
        const float4* __restrict__ centers4,   // [B*F]
        unsigned int* __restrict__ keys) {     // [B*N], pre-set to 0xFFFFFFFF
    __shared__ float4 sc[SLICE_F];

    const int chunk = blockIdx.x;
    const int s     = blockIdx.y;
    const int b     = blockIdx.z;
    const int tid   = threadIdx.x;

    const float4* cb = centers4 + b * NF + s * SLICE_F;
    for (int i = tid; i < SLICE_F; i += TPB) sc[i] = cb[i];
    __syncthreads();

    float m2x[PPT], m2y[PPT], m2z[PPT], p2[PPT], bd[PPT];
    int   bi[PPT], pn[PPT];
#pragma unroll
    for (int j = 0; j < PPT; ++j) {
        int nn = chunk * CHUNK_P + j * TPB + tid;
        pn[j] = nn;
        const float* pp = pred + ((size_t)b * NP + nn) * 3;
        float x = pp[0], y = pp[1], z = pp[2];
        m2x[j] = -2.0f * x;
        m2y[j] = -2.0f * y;
        m2z[j] = -2.0f * z;
        p2[j]  = x * x + y * y + z * z;
        bd[j]  = 1e30f;
        bi[j]  = 0;
    }

    for (int f = 0; f < SLICE_F; ++f) {
        float4 c = sc[f];   // wave-uniform address -> LDS broadcast
#pragma unroll
        for (int j = 0; j < PPT; ++j) {
            float d = fmaf(m2x[j], c.x,
                      fmaf(m2y[j], c.y,
                      fmaf(m2z[j], c.z, c.w)));
            if (d < bd[j]) { bd[j] = d; bi[j] = f; }   // strict < keeps first
        }
    }

#pragma unroll
    for (int j = 0; j < PPT; ++j) {
        float d2 = fmaxf(bd[j] + p2[j], 0.0f);
        unsigned key = (__float_as_uint(d2) & 0xFFFFC000u) |
                       (unsigned)(s * SLICE_F + bi[j]);
        atomicMin(&keys[b * NP + pn[j]], key);
    }
}

// ---------------------------------------------------------------------------
// Kernel C: per-point signed plane distance -> interp^3 sum + hit count.
// ---------------------------------------------------------------------------
__global__ __launch_bounds__(TPB) void finalize_kernel(
        const float* __restrict__ pred,
        const float4* __restrict__ centers4,
        const float4* __restrict__ normals4,
        const unsigned int* __restrict__ keys,
        float* __restrict__ acc) {   // acc[0]=sum interp^3, acc[1]=count
    int i = blockIdx.x * blockDim.x + threadIdx.x;   // 0 .. B*N-1
    float val = 0.0f, cnt = 0.0f;
    if (i < NB * NP) {
        int b = i / NP;
        unsigned key = keys[i];
        int idx = (int)(key & (unsigned)(NF - 1));
        float4 c  = centers4[b * NF + idx];
        float4 nr = normals4[b * NF + idx];
        const float* pp = pred + (size_t)i * 3;
        float dx = pp[0] - c.x, dy = pp[1] - c.y, dz = pp[2] - c.z;
        float dist = dx * nr.x + dy * nr.y + dz * nr.z;
        float t = F_EPS - dist;
        if (t > 0.0f) { cnt = 1.0f; val = t * t * t; }
    }
    // wave reduce (64 lanes) then cross-wave via LDS
    for (int off = 32; off > 0; off >>= 1) {
        val += __shfl_down(val, off, 64);
        cnt += __shfl_down(cnt, off, 64);
    }
    __shared__ float sv[TPB / 64], sn[TPB / 64];
    int lane = threadIdx.x & 63, wave = threadIdx.x >> 6;
    if (lane == 0) { sv[wave] = val; sn[wave] = cnt; }
    __syncthreads();
    if (threadIdx.x == 0) {
        float v = 0.0f, cc = 0.0f;
#pragma unroll
        for (int w = 0; w < TPB / 64; ++w) { v += sv[w]; cc += sn[w]; }
        atomicAdd(&acc[0], v);
        atomicAdd(&acc[1], cc);
    }
}

// ---------------------------------------------------------------------------
// Kernel D: scalars -> d_out  (loss, perc)
// ---------------------------------------------------------------------------
__global__ void out_kernel(const float* __restrict__ acc,
                           float* __restrict__ out) {
    if (threadIdx.x == 0) {
        out[0] = acc[0] * (F_WEIGHT / (float)NB);          // mean over B of sums * weight
        out[1] = acc[1] * (1.0f / (float)(NB * NP));       // fraction of hits
    }
}

extern "C" void kernel_launch(void* const* d_in, const int* in_sizes, int n_in,
                              void* d_out, int out_size, void* d_ws, size_t ws_size,
                              hipStream_t stream) {
    const float* pred  = (const float*)d_in[0];   // [B,N,3] f32
    const float* opos  = (const float*)d_in[1];   // [B,V,3] f32
    const int*   faces = (const int*)  d_in[2];   // [B,F,3] i32

    char* ws = (char*)d_ws;
    const size_t centers_bytes = (size_t)NB * NF * sizeof(float4);  // 1 MiB
    float4*       centers4 = (float4*)ws;
    float4*       normals4 = (float4*)(ws + centers_bytes);
    unsigned int* keys     = (unsigned int*)(ws + 2 * centers_bytes);
    float*        acc      = (float*)(ws + 2 * centers_bytes +
                                      (size_t)NB * NP * sizeof(unsigned int));

    hipMemsetAsync(keys, 0xFF, (size_t)NB * NP * sizeof(unsigned int), stream);
    hipMemsetAsync(acc, 0, 2 * sizeof(float), stream);

    centers_kernel<<<(NB * NF + 255) / 256, 256, 0, stream>>>(
        opos, faces, centers4, normals4);

    nn_kernel<<<dim3(CHUNKS, SLICES, NB), TPB, 0, stream>>>(
        pred, centers4, keys);

    finalize_kernel<<<(NB * NP + TPB - 1) / TPB, TPB, 0, stream>>>(
        pred, centers4, normals4, keys, acc);

    out_kernel<<<1, 64, 0, stream>>>(acc, (float*)d_out);
}

// Round 2
// 124.092 us; speedup vs baseline: 1.6909x; 1.6909x over previous
//
#include <hip/hip_runtime.h>
#include <cstdint>

typedef __attribute__((ext_vector_type(8))) short short8;
typedef __attribute__((ext_vector_type(4))) float floatx4;

constexpr int NB = 4;        // batch
constexpr int NV = 8192;     // vertices
constexpr int NF = 16384;    // faces
constexpr int NP = 8192;     // query points per batch
constexpr float F_EPS = 1e-3f;
constexpr float F_WEIGHT = 1000.0f;
constexpr float BIAS = 1e-3f;        // keeps dist^2 > 0 despite bf16-hi/lo rounding

constexpr int PT_TILES = NP / 16;    // 512 point tiles / batch
constexpr int FC_TILES = NF / 16;    // 1024 face tiles / batch
constexpr int TPB = 256;             // 4 waves
constexpr int TPW = 4;               // point tiles per wave (64 points/wave)
constexpr int FS = 8;                // face slices (cross-slice merge by atomicMin)
constexpr int SL_TILES = FC_TILES / FS;     // 128 tiles per slice
constexpr int CH_TILES = 32;                // tiles per LDS chunk (32 KB)
constexpr int NCHUNK = SL_TILES / CH_TILES; // 4

union FragU { uint4 u; short8 s; };

__device__ inline unsigned f2bf(float f) {           // fp32 -> bf16 (RNE)
    unsigned u = __float_as_uint(f);
    return (u + 0x7FFFu + ((u >> 16) & 1u)) >> 16;
}
__device__ inline float bf2f(unsigned h) { return __uint_as_float(h << 16); }
__device__ inline unsigned pk(unsigned lo, unsigned hi) {
    return (lo & 0xFFFFu) | (hi << 16);
}

// ---------------------------------------------------------------------------
// A-fragments from pred points. K-slot map (per point m):
//  k0..2  = -2*p_hi.xyz   k3..5 = -2*p_lo.xyz   k6..8 = -2*p_hi.xyz
//  k9..11 = -2*p_lo.xyz   k12=1  k13=1  k14=p2b_hi  k15=p2b_lo   (k16..31 = 0)
// Lane L of a tile holds A[m=L&15][k=(L>>4)*8 + j], j=0..7, as 8 bf16 = 16B.
// Also folds the keys / acc initialization (saves two memset dispatches).
// ---------------------------------------------------------------------------
__global__ void points_prep(const float* __restrict__ pred,
                            uint4* __restrict__ a_frags,
                            unsigned* __restrict__ keys,
                            float* __restrict__ acc) {
    int i = blockIdx.x * blockDim.x + threadIdx.x;   // [0, NB*NP)
    if (i >= NB * NP) return;
    keys[i] = 0xFFFFFFFFu;
    if (i < 2) acc[i] = 0.0f;

    int b = i / NP, n = i & (NP - 1);
    float x = pred[3 * (size_t)i], y = pred[3 * (size_t)i + 1], z = pred[3 * (size_t)i + 2];
    unsigned hx = f2bf(x), hy = f2bf(y), hz = f2bf(z);
    float rx = x - bf2f(hx), ry = y - bf2f(hy), rz = z - bf2f(hz);
    unsigned ahx = f2bf(-2.f * bf2f(hx)), ahy = f2bf(-2.f * bf2f(hy)), ahz = f2bf(-2.f * bf2f(hz));
    unsigned alx = f2bf(-2.f * rx), aly = f2bf(-2.f * ry), alz = f2bf(-2.f * rz);
    float p2 = x * x + y * y + z * z + BIAS;
    unsigned p2h = f2bf(p2);
    unsigned p2l = f2bf(p2 - bf2f(p2h));
    const unsigned ONE = 0x3F80u;

    int tile = n >> 4, m = n & 15;
    uint4* base = a_frags + (size_t)(b * PT_TILES + tile) * 64;
    base[m]      = make_uint4(pk(ahx, ahy), pk(ahz, alx), pk(aly, alz), pk(ahx, ahy));
    base[16 + m] = make_uint4(pk(ahz, alx), pk(aly, alz), pk(ONE, ONE), pk(p2h, p2l));
    base[32 + m] = make_uint4(0, 0, 0, 0);   // quads 2,3: k=16..31 zero
    base[48 + m] = make_uint4(0, 0, 0, 0);
}

// ---------------------------------------------------------------------------
// B-fragments + centers/normals from faces. K-slot map (per face n):
//  k0..2 = c_hi.xyz  k3..5 = c_hi.xyz  k6..8 = c_lo.xyz  k9..11 = c_lo.xyz
//  k12=c2_hi  k13=c2_lo  k14=1  k15=1   (k16..31 = 0)
// => MFMA D[m][n] = p2b[m] + c2[n] - 2 p[m].c[n]  =  dist^2 + BIAS  > 0
// ---------------------------------------------------------------------------
__global__ void faces_prep(const float* __restrict__ pos,    // [B,V,3]
                           const int*   __restrict__ faces,  // [B,F,3]
                           uint4*  __restrict__ b_frags,
                           float4* __restrict__ centers4,
                           float4* __restrict__ normals4) {
    int i = blockIdx.x * blockDim.x + threadIdx.x;   // [0, NB*NF)
    if (i >= NB * NF) return;
    int b = i / NF, f = i & (NF - 1);
    const float* p = pos + (size_t)b * NV * 3;
    int i0 = faces[3 * (size_t)i], i1 = faces[3 * (size_t)i + 1], i2 = faces[3 * (size_t)i + 2];
    float ax = p[3 * i0], ay = p[3 * i0 + 1], az = p[3 * i0 + 2];
    float bx = p[3 * i1], by = p[3 * i1 + 1], bz = p[3 * i1 + 2];
    float cx = p[3 * i2], cy = p[3 * i2 + 1], cz = p[3 * i2 + 2];

    const float third = 1.0f / 3.0f;
    float mx = (ax + bx + cx) * third;
    float my = (ay + by + cy) * third;
    float mz = (az + bz + cz) * third;
    float c2 = mx * mx + my * my + mz * mz;

    float e1x = bx - ax, e1y = by - ay, e1z = bz - az;
    float e2x = cx - ax, e2y = cy - ay, e2z = cz - az;
    float nx = e1y * e2z - e1z * e2y;
    float ny = e1z * e2x - e1x * e2z;
    float nz = e1x * e2y - e1y * e2x;
    float len = sqrtf(nx * nx + ny * ny + nz * nz);
    float inv = 1.0f / fmaxf(len, 1e-12f);

    centers4[i] = make_float4(mx, my, mz, c2);
    normals4[i] = make_float4(nx * inv, ny * inv, nz * inv, 0.0f);

    unsigned bhx = f2bf(mx), bhy = f2bf(my), bhz = f2bf(mz);
    unsigned blx = f2bf(mx - bf2f(bhx)), bly = f2bf(my - bf2f(bhy)), blz = f2bf(mz - bf2f(bhz));
    unsigned c2h = f2bf(c2);
    unsigned c2l = f2bf(c2 - bf2f(c2h));
    const unsigned ONE = 0x3F80u;

    int tile = f >> 4, m = f & 15;
    uint4* base = b_frags + (size_t)(b * FC_TILES + tile) * 64;
    base[m]      = make_uint4(pk(bhx, bhy), pk(bhz, bhx), pk(bhy, bhz), pk(blx, bly));
    base[16 + m] = make_uint4(pk(blz, blx), pk(bly, blz), pk(c2h, c2l), pk(ONE, ONE));
    base[32 + m] = make_uint4(0, 0, 0, 0);
    base[48 + m] = make_uint4(0, 0, 0, 0);
}

// ---------------------------------------------------------------------------
// 1-NN scan on the matrix pipe. Block = (point-group of 256 pts, F-slice, b).
// Each wave owns 4 point tiles (A-frags in regs); face tiles stream through
// LDS; per MFMA the epilogue is 4x (v_and_or_b32 + v_min_u32) on packed keys
//   key = (bits(dist^2+BIAS) & 0xFFFFC000) | face_idx   (14 idx bits, F=16384)
// Cross-lane min within 16-lane col groups, then one atomicMin per point/slice.
// ---------------------------------------------------------------------------
__global__ __launch_bounds__(TPB) void nn_kernel(
        const uint4* __restrict__ a_frags,
        const uint4* __restrict__ b_frags,
        unsigned* __restrict__ keys) {
    __shared__ uint4 sb[CH_TILES * 64];          // 32 KB

    const int pg   = blockIdx.x;                 // 0..31  (256 points each)
    const int sl   = blockIdx.y;                 // 0..7   (2048 faces each)
    const int b    = blockIdx.z;
    const int tid  = threadIdx.x;
    const int wave = tid >> 6;
    const int lane = tid & 63;
    const int col  = lane & 15;

    FragU a[TPW];
    const int base_t = b * PT_TILES + pg * 16 + wave * TPW;
#pragma unroll
    for (int t = 0; t < TPW; ++t)
        a[t].u = a_frags[(size_t)(base_t + t) * 64 + lane];

    unsigned best[TPW * 4];
#pragma unroll
    for (int e = 0; e < TPW * 4; ++e) best[e] = 0xFFFFFFFFu;

    const floatx4 zero = {0.f, 0.f, 0.f, 0.f};

    for (int ch = 0; ch < NCHUNK; ++ch) {
        const size_t g0 = (size_t)(b * FC_TILES + sl * SL_TILES + ch * CH_TILES) * 64;
        for (int idx = tid; idx < CH_TILES * 64; idx += TPB)
            sb[idx] = b_frags[g0 + idx];
        __syncthreads();

        unsigned vface = (unsigned)(sl * (SL_TILES * 16) + ch * (CH_TILES * 16) + col);
        for (int t = 0; t < CH_TILES; ++t) {
            FragU bu;
            bu.u = sb[t * 64 + lane];
#pragma unroll
            for (int tt = 0; tt < TPW; ++tt) {
                floatx4 d = __builtin_amdgcn_mfma_f32_16x16x32_bf16(
                    a[tt].s, bu.s, zero, 0, 0, 0);
#pragma unroll
                for (int r = 0; r < 4; ++r) {
                    unsigned key = (__float_as_uint(d[r]) & 0xFFFFC000u) | vface;
                    best[tt * 4 + r] = min(best[tt * 4 + r], key);
                }
            }
            vface += 16;
        }
        __syncthreads();
    }

    // reduce across the 16 columns (lanes sharing a quad)
#pragma unroll
    for (int e = 0; e < TPW * 4; ++e) {
        unsigned v = best[e];
#pragma unroll
        for (int m = 1; m < 16; m <<= 1)
            v = min(v, (unsigned)__shfl_xor((int)v, m, 64));
        best[e] = v;
    }
    if (col == 0) {
        int q = lane >> 4;
#pragma unroll
        for (int tt = 0; tt < TPW; ++tt)
#pragma unroll
            for (int r = 0; r < 4; ++r) {
                int n = (pg * 16 + wave * TPW + tt) * 16 + q * 4 + r;
                atomicMin(&keys[b * NP + n], best[tt * 4 + r]);
            }
    }
}

// ---------------------------------------------------------------------------
// Per-point signed plane distance -> interp^3 sum + hit count.
// ---------------------------------------------------------------------------
__global__ __launch_bounds__(TPB) void finalize_kernel(
        const float* __restrict__ pred,
        const float4* __restrict__ centers4,
        const float4* __restrict__ normals4,
        const unsigned int* __restrict__ keys,
        float* __restrict__ acc) {
    int i = blockIdx.x * blockDim.x + threadIdx.x;   // 0 .. B*N-1
    float val = 0.0f, cnt = 0.0f;
    if (i < NB * NP) {
        int b = i / NP;
        unsigned key = keys[i];
        int idx = (int)(key & (unsigned)(NF - 1));
        float4 c  = centers4[b * NF + idx];
        float4 nr = normals4[b * NF + idx];
        const float* pp = pred + (size_t)i * 3;
        float dx = pp[0] - c.x, dy = pp[1] - c.y, dz = pp[2] - c.z;
        float dist = dx * nr.x + dy * nr.y + dz * nr.z;
        float t = F_EPS - dist;
        if (t > 0.0f) { cnt = 1.0f; val = t * t * t; }
    }
    for (int off = 32; off > 0; off >>= 1) {
        val += __shfl_down(val, off, 64);
        cnt += __shfl_down(cnt, off, 64);
    }
    __shared__ float sv[TPB / 64], sn[TPB / 64];
    int lane = threadIdx.x & 63, wave = threadIdx.x >> 6;
    if (lane == 0) { sv[wave] = val; sn[wave] = cnt; }
    __syncthreads();
    if (threadIdx.x == 0) {
        float v = 0.0f, cc = 0.0f;
#pragma unroll
        for (int w = 0; w < TPB / 64; ++w) { v += sv[w]; cc += sn[w]; }
        atomicAdd(&acc[0], v);
        atomicAdd(&acc[1], cc);
    }
}

__global__ void out_kernel(const float* __restrict__ acc,
                           float* __restrict__ out) {
    if (threadIdx.x == 0) {
        out[0] = acc[0] * (F_WEIGHT / (float)NB);
        out[1] = acc[1] * (1.0f / (float)(NB * NP));
    }
}

extern "C" void kernel_launch(void* const* d_in, const int* in_sizes, int n_in,
                              void* d_out, int out_size, void* d_ws, size_t ws_size,
                              hipStream_t stream) {
    const float* pred  = (const float*)d_in[0];   // [B,N,3] f32
    const float* opos  = (const float*)d_in[1];   // [B,V,3] f32
    const int*   faces = (const int*)  d_in[2];   // [B,F,3] i32

    char* ws = (char*)d_ws;
    const size_t a_bytes = (size_t)NB * PT_TILES * 64 * 16;   // 2 MiB
    const size_t b_bytes = (size_t)NB * FC_TILES * 64 * 16;   // 4 MiB
    const size_t c_bytes = (size_t)NB * NF * 16;              // 1 MiB

    uint4*    a_frags  = (uint4*)ws;
    uint4*    b_frags  = (uint4*)(ws + a_bytes);
    float4*   centers4 = (float4*)(ws + a_bytes + b_bytes);
    float4*   normals4 = (float4*)(ws + a_bytes + b_bytes + c_bytes);
    unsigned* keys     = (unsigned*)(ws + a_bytes + b_bytes + 2 * c_bytes);
    float*    acc      = (float*)(ws + a_bytes + b_bytes + 2 * c_bytes +
                                  (size_t)NB * NP * sizeof(unsigned));

    points_prep<<<(NB * NP + TPB - 1) / TPB, TPB, 0, stream>>>(
        pred, a_frags, keys, acc);
    faces_prep<<<(NB * NF + TPB - 1) / TPB, TPB, 0, stream>>>(
        opos, faces, b_frags, centers4, normals4);

    nn_kernel<<<dim3(NP / 256, FS, NB), TPB, 0, stream>>>(
        a_frags, b_frags, keys);

    finalize_kernel<<<(NB * NP + TPB - 1) / TPB, TPB, 0, stream>>>(
        pred, centers4, normals4, keys, acc);

    out_kernel<<<1, 64, 0, stream>>>(acc, (float*)d_out);
}